// Round 7
// baseline (3869.476 us; speedup 1.0000x reference)
//
// R18: un-stall the scan step. R17 post-mortem: 5.6us/step vs ~3us model.
// Suspects in-code: (1) ds_read_b128 in k-loop un-pipelined at VGPR=256 cap
// (up to 16x120cyc exposed LDS latency) -> explicit double-buffered af reads;
// (2) 16 staged 64-bit addr recomputes/step + 32-VGPR st_row/st_ch -> 16
// precomputed element offsets (addr = base + off + tt*1024), same for xz/text;
// (3) xz prefetch after poll = serial HBM tail -> issue between flag store and
// poll (hidden under flag RTT); (4) block drain + single signaller -> per-WAVE
// flags (128/dir): wave drains own vmcnt, lane0 signals, poll = one 8B AGENT
// load/lane; one post-poll __syncthreads replaces the pre-flag block drain
// (s_h WAR: all waves passed poll => finished MFMA reads; barrier before DMA).
// Protocol scopes unchanged (AGENT atomics = proven). Placement b%8, DMA
// staging w/ source-side XOR, in-reg gates, GEMMs, carve: identical to R17.
#include <hip/hip_runtime.h>
#include <hip/hip_fp16.h>
#include <math.h>

#define NB   64
#define NS   256
#define ND   300
#define NDP  320
#define NH   512
#define N4H  2048

typedef _Float16 half8_t __attribute__((ext_vector_type(8)));
typedef float    f32x4_t __attribute__((ext_vector_type(4)));

typedef const __attribute__((address_space(1))) unsigned int gas_u32;
typedef __attribute__((address_space(3))) unsigned int las_u32;

__device__ __forceinline__ float fast_sig(float x) {
  return 1.f / (1.f + __expf(-x));
}
__device__ __forceinline__ float fast_tanh(float x) {
  float ax = fabsf(x);
  float e  = __expf(2.f * ax);          // inf for large ax -> r -> 1
  float r  = 1.f - 2.f / (e + 1.f);
  return copysignf(r, x);
}

// ---------- embedding: gather + fp16 convert + zero-pad K to 320 ----------
__global__ void embed_f16_kernel(const int* __restrict__ text,
                                 const float* __restrict__ emb,
                                 _Float16* __restrict__ x) {
  int idx = blockIdx.x * 256 + threadIdx.x;
  const int total = NB * NS * NDP;
  for (; idx < total; idx += gridDim.x * 256) {
    int bs = idx / NDP;
    int d  = idx - bs * NDP;
    x[idx] = (d < ND) ? (_Float16)emb[(size_t)text[bs] * ND + d] : (_Float16)0.f;
  }
}

// ---------- MFMA GEMM with in-LDS weight transpose (unchanged from R6) ----------
__global__ __launch_bounds__(256) void gemm_mfma_kernel(
    const _Float16* __restrict__ A, const float* __restrict__ W,
    const float* __restrict__ bias, __half* __restrict__ C,
    int M, int N, int K, int Kw) {
  __shared__ __align__(16) _Float16 as[128][40];
  __shared__ __align__(16) _Float16 ws16[128][40];
  __shared__ __align__(16) float    ws32[32][132];
  const int t = threadIdx.x;
  const int w = t >> 6;
  const int l = t & 63;
  const int lane16 = l & 15;
  const int kq = l >> 4;
  const int bm = blockIdx.y * 128;
  const int bn = blockIdx.x * 128;
  const int lr  = t >> 2;
  const int lsg = t & 3;
  const int wk  = t >> 3;
  const int wns = t & 7;
  const int rn  = t >> 1;
  const int rk0 = (t & 1) * 2;

  f32x4_t acc[2][8];
#pragma unroll
  for (int i = 0; i < 2; i++)
#pragma unroll
    for (int j = 0; j < 8; j++) acc[i][j] = (f32x4_t){0.f, 0.f, 0.f, 0.f};

  for (int k0 = 0; k0 < K; k0 += 32) {
#pragma unroll
    for (int h = 0; h < 2; h++) {
      int m = h * 64 + lr;
      *(uint4*)&as[m][lsg * 8] = *(const uint4*)(A + (size_t)(bm + m) * K + k0 + lsg * 8);
    }
    if (k0 + wk < Kw) {
#pragma unroll
      for (int i = 0; i < 4; i++)
        *(float4*)&ws32[wk][wns * 16 + i * 4] =
            *(const float4*)(W + (size_t)(k0 + wk) * N + bn + wns * 16 + i * 4);
    } else {
#pragma unroll
      for (int i = 0; i < 4; i++)
        *(float4*)&ws32[wk][wns * 16 + i * 4] = make_float4(0.f, 0.f, 0.f, 0.f);
    }
    __syncthreads();
#pragma unroll
    for (int g = 0; g < 2; g++) {
      int kqq = rk0 + g;
      half8_t hv;
#pragma unroll
      for (int jj = 0; jj < 8; jj++) hv[jj] = (_Float16)ws32[kqq * 8 + jj][rn];
      *(half8_t*)&ws16[rn][kqq * 8] = hv;
    }
    __syncthreads();
    half8_t afrag[2];
#pragma unroll
    for (int i = 0; i < 2; i++)
      afrag[i] = *(const half8_t*)&as[w * 32 + i * 16 + lane16][kq * 8];
#pragma unroll
    for (int j = 0; j < 8; j++) {
      half8_t bfrag = *(const half8_t*)&ws16[j * 16 + lane16][kq * 8];
#pragma unroll
      for (int i = 0; i < 2; i++)
        acc[i][j] = __builtin_amdgcn_mfma_f32_16x16x32_f16(afrag[i], bfrag, acc[i][j], 0, 0, 0);
    }
    __syncthreads();
  }
#pragma unroll
  for (int j = 0; j < 8; j++) {
    int col = bn + j * 16 + lane16;
    float bv = bias[col];
#pragma unroll
    for (int i = 0; i < 2; i++) {
      int rbase = bm + w * 32 + i * 16 + kq * 4;
#pragma unroll
      for (int r = 0; r < 4; r++)
        C[(size_t)(rbase + r) * N + col] = __float2half(acc[i][j][r] + bv);
    }
  }
}

// ---------- persistent bi-LSTM scan ----------
// Grid 256 x 256thr. Block b participates iff (b&7)<2: dir=b&7, cblk=b>>3.
// Same-direction blocks co-located on one XCD (b%8, proven R14).
// Flags: per-WAVE, flags[dir*128 + cblk*4 + w], value = steps completed.
// Wave signals after its own vmcnt drain; poll = one 8B AGENT load per lane
// (lane covers flags 2*lane, 2*lane+1); post-poll __syncthreads re-joins the
// block before the next staging DMA overwrites s_h.
#define PREFETCH_NEXT(TTN)                                                    \
  {                                                                           \
    const size_t xzstep = (size_t)(TTN) * N4H;                                \
    _Pragma("unroll")                                                         \
    for (int k = 0; k < 16; k++) xzr[k] = xz[xzstep + xz_off[k]];             \
    _Pragma("unroll")                                                         \
    for (int r4 = 0; r4 < 4; r4++) tmsk[r4] = text[t_off[r4] + (TTN)];        \
  }

__global__ __launch_bounds__(256, 1) void scan_ring_kernel(
    const __half* __restrict__ xzf, const __half* __restrict__ xzb,
    const float* __restrict__ Uf, const float* __restrict__ Ub,
    const int* __restrict__ text,
    __half* ring,
    int* flags, int* abortf,
    float* __restrict__ hT_out) {
  __shared__ __align__(16) _Float16 s_h[64 * 512];   // 64KB h tile (chunk q at q*16B)

  const int t  = threadIdx.x;
  const int b  = blockIdx.x;
  const int grp = b & 7;
  if (grp >= 2) return;                // blocks on XCD2..7: exit immediately
  const int dir  = grp;
  const int cblk = b >> 3;             // 0..31
  const int hc0  = cblk * 16;
  const __half* xz = dir ? xzb : xzf;
  const float* U = dir ? Ub : Uf;
  int* myflags = flags + dir * 128;

  const int w    = t >> 6;          // wave = m-tile (rows w*16..w*16+16)
  const int lane = t & 63;
  const int l16  = lane & 15;
  const int quad = lane >> 4;

  // staging geometry collapsed to element offsets (chunk q = i*256 + t):
  // src elem = dir*NH + st_off[i] + ttp*1024, st_off = row*NS*1024 + ch_src*8
  int st_off[16];
#pragma unroll
  for (int i = 0; i < 16; i++) {
    int q = i * 256 + t;
    st_off[i] = (q >> 6) * (NS * 1024) + (((q & 63) ^ (q >> 6)) * 8);
  }
  const __half* ringd = ring + dir * NH;

  // xz/text prefetch offsets (element units; max ~33M < 2^31)
  const int row0 = w * 16 + quad * 4;
  int xz_off[16], t_off[4];
#pragma unroll
  for (int nt = 0; nt < 4; nt++)
#pragma unroll
    for (int r4 = 0; r4 < 4; r4++)
      xz_off[nt * 4 + r4] = (row0 + r4) * (NS * N4H) + nt * NH + hc0 + l16;
#pragma unroll
  for (int r4 = 0; r4 < 4; r4++) t_off[r4] = (row0 + r4) * NS;

  // persistent U B-frags: ufrag[kt][nt][jj] = U[kt*32+quad*8+jj][nt*512+hc0+l16]
  half8_t ufrag[16][4];
#pragma unroll
  for (int nt = 0; nt < 4; nt++) {
    int col = nt * NH + hc0 + l16;
#pragma unroll
    for (int kt = 0; kt < 16; kt++)
#pragma unroll
      for (int jj = 0; jj < 8; jj++)
        ufrag[kt][nt][jj] = (_Float16)U[(size_t)(kt * 32 + quad * 8 + jj) * N4H + col];
  }

  // LSTM state in MFMA layout: thread owns rows row0..row0+3, col hc0+l16
  float c_st[4] = {0.f, 0.f, 0.f, 0.f}, h_st[4] = {0.f, 0.f, 0.f, 0.f};

  // prefetch registers: xz (16 scalars) + mask (4 ints), step-s values
  __half xzr[16];
  int    tmsk[4];
  {
    const int tt0 = dir ? (NS - 1) : 0;
    PREFETCH_NEXT(tt0);
  }

  for (int s = 0; s < NS; s++) {
    const int tt = dir ? (NS - 1 - s) : s;
    f32x4_t acc[4] = {{0.f,0.f,0.f,0.f},{0.f,0.f,0.f,0.f},{0.f,0.f,0.f,0.f},{0.f,0.f,0.f,0.f}};

    if (s > 0) {
      const int ttp = dir ? (tt + 1) : (tt - 1);   // slot holding h(s-1)
      const __half* srcb = ringd + (size_t)ttp * 1024;
      // stage h(s-1): 16x 16B DMA per thread from home-XCD L2, all in flight.
#pragma unroll
      for (int i = 0; i < 16; i++) {
        __builtin_amdgcn_global_load_lds((gas_u32*)(srcb + st_off[i]),
                                         (las_u32*)(s_h + (size_t)(i * 256 + t) * 8),
                                         16, 0, 0);
      }
      __syncthreads();   // drains DMA (vmcnt); prefetch loads long since done
      const int r = w * 16 + l16;
      // double-buffered A-frag reads: ds_read for kt+1 issued before kt's MFMAs
      half8_t af = *(const half8_t*)(s_h + r * 512 + ((0 * 4 + quad) ^ r) * 8);
#pragma unroll
      for (int kt = 0; kt < 16; kt++) {
        half8_t afn;
        if (kt < 15)
          afn = *(const half8_t*)(s_h + r * 512 + (((kt + 1) * 4 + quad) ^ r) * 8);
#pragma unroll
        for (int nt = 0; nt < 4; nt++)
          acc[nt] = __builtin_amdgcn_mfma_f32_16x16x32_f16(af, ufrag[kt][nt], acc[nt], 0, 0, 0);
        af = afn;
      }
    }

    // gates directly in MFMA register layout; no LDS transpose.
    // acc[nt][r4] = z[row0+r4][nt*16+l16]; gate i/f/g/o == nt 0/1/2/3.
#pragma unroll
    for (int r4 = 0; r4 < 4; r4++) {
      float zi = acc[0][r4] + __half2float(xzr[0  + r4]);
      float zf = acc[1][r4] + __half2float(xzr[4  + r4]);
      float zg = acc[2][r4] + __half2float(xzr[8  + r4]);
      float zo = acc[3][r4] + __half2float(xzr[12 + r4]);
      float ig = fast_sig(zi);
      float fg = fast_sig(zf);
      float gv = fast_tanh(zg);
      float og = fast_sig(zo);
      float cn = fg * c_st[r4] + ig * gv;
      float hn = og * fast_tanh(cn);
      if (tmsk[r4] != 0) { c_st[r4] = cn; h_st[r4] = hn; }
      // plain 2B store: write-through L1 -> ack at shared home-XCD L2
      ring[((size_t)(row0 + r4) * NS + tt) * 1024 + dir * NH + hc0 + l16] =
          __float2half(h_st[r4]);
    }
    if (hT_out && s == NS - 1) {
#pragma unroll
      for (int r4 = 0; r4 < 4; r4++)
        hT_out[(size_t)(row0 + r4) * 1024 + dir * NH + hc0 + l16] = h_st[r4];
    }

    if (s < NS - 1) {
      const int ttn = dir ? (tt - 1) : (tt + 1);
      // per-wave signal: drain THIS wave's h stores (ack at home L2), flag it
      asm volatile("s_waitcnt vmcnt(0)" ::: "memory");
      if (lane == 0)
        __hip_atomic_store(myflags + cblk * 4 + w, s + 1, __ATOMIC_RELAXED,
                           __HIP_MEMORY_SCOPE_AGENT);
      // prefetch next xz/mask NOW: HBM latency hides under the flag RTT
      PREFETCH_NEXT(ttn);
      // poll all 128 wave-flags of this dir: one 8B AGENT load per lane
      {
        const unsigned long long* fp64 =
            (const unsigned long long*)myflags + lane;
        int aborted = 0, it = 0;
        while (true) {
          unsigned long long v = __hip_atomic_load(fp64, __ATOMIC_RELAXED,
                                                   __HIP_MEMORY_SCOPE_AGENT);
          int lo = (int)(unsigned)(v & 0xffffffffull);
          int hi = (int)(unsigned)(v >> 32);
          if (__all(lo >= s + 1 && hi >= s + 1)) break;
          __builtin_amdgcn_s_sleep(1);
          if (((++it) & 1023) == 0) {
            if (it > 200000)
              __hip_atomic_store(abortf, 1, __ATOMIC_RELAXED, __HIP_MEMORY_SCOPE_AGENT);
            if (__hip_atomic_load(abortf, __ATOMIC_RELAXED, __HIP_MEMORY_SCOPE_AGENT)) {
              aborted = 1; break;
            }
          }
        }
        if (aborted) return;   // wave-uniform; before any barrier -> no hang
      }
      __syncthreads();   // re-join block before next DMA overwrites s_h
                         // (cheap: waves aligned by poll; prefetch already done)
    }
  }
}

// ---------- fp32 SMEM GEMM (head only) ----------
template <int ACT>
__global__ __launch_bounds__(256) void gemm_kernel(
    const float* __restrict__ A, const float* __restrict__ W,
    const float* __restrict__ bias, float* __restrict__ C,
    int M, int N, int K) {
  __shared__ __align__(16) float As[8][128];
  __shared__ __align__(16) float Bs[8][128];
  const int t  = threadIdx.x;
  const int bn = blockIdx.x * 128;
  const int bm = blockIdx.y * 128;
  const int tx = t & 15, ty = t >> 4;
  const int lm  = t >> 1;
  const int lk4 = (t & 1) * 4;
  const int lbk = t >> 5;
  const int lbn = (t & 31) * 4;
  float acc[8][8];
#pragma unroll
  for (int i = 0; i < 8; i++)
#pragma unroll
    for (int j = 0; j < 8; j++) acc[i][j] = 0.f;

  for (int k0 = 0; k0 < K; k0 += 8) {
#pragma unroll
    for (int i = 0; i < 4; i++) {
      int k = k0 + lk4 + i;
      int m = bm + lm;
      float v = 0.f;
      if (k < K && m < M) v = A[(size_t)m * K + k];
      As[lk4 + i][lm] = v;
    }
    {
      int k = k0 + lbk;
      float4 v = make_float4(0.f, 0.f, 0.f, 0.f);
      if (k < K) v = *(const float4*)(W + (size_t)k * N + bn + lbn);
      *(float4*)(&Bs[lbk][lbn]) = v;
    }
    __syncthreads();
#pragma unroll
    for (int kk = 0; kk < 8; kk++) {
      float a[8], bb[8];
      *(float4*)(a)      = *(const float4*)(&As[kk][ty * 8]);
      *(float4*)(a + 4)  = *(const float4*)(&As[kk][ty * 8 + 4]);
      *(float4*)(bb)     = *(const float4*)(&Bs[kk][tx * 8]);
      *(float4*)(bb + 4) = *(const float4*)(&Bs[kk][tx * 8 + 4]);
#pragma unroll
      for (int i = 0; i < 8; i++)
#pragma unroll
        for (int j = 0; j < 8; j++) acc[i][j] += a[i] * bb[j];
    }
    __syncthreads();
  }
  float4 bv0 = *(const float4*)(bias + bn + tx * 8);
  float4 bv1 = *(const float4*)(bias + bn + tx * 8 + 4);
#pragma unroll
  for (int i = 0; i < 8; i++) {
    int m = bm + ty * 8 + i;
    if (m >= M) continue;
    float4 o0, o1;
    o0.x = acc[i][0] + bv0.x; o0.y = acc[i][1] + bv0.y;
    o0.z = acc[i][2] + bv0.z; o0.w = acc[i][3] + bv0.w;
    o1.x = acc[i][4] + bv1.x; o1.y = acc[i][5] + bv1.y;
    o1.z = acc[i][6] + bv1.z; o1.w = acc[i][7] + bv1.w;
    if (ACT == 1) {
      o0.x = o0.x >= 0.f ? o0.x : 0.2f * o0.x;  o0.y = o0.y >= 0.f ? o0.y : 0.2f * o0.y;
      o0.z = o0.z >= 0.f ? o0.z : 0.2f * o0.z;  o0.w = o0.w >= 0.f ? o0.w : 0.2f * o0.w;
      o1.x = o1.x >= 0.f ? o1.x : 0.2f * o1.x;  o1.y = o1.y >= 0.f ? o1.y : 0.2f * o1.y;
      o1.z = o1.z >= 0.f ? o1.z : 0.2f * o1.z;  o1.w = o1.w >= 0.f ? o1.w : 0.2f * o1.w;
    }
    *(float4*)(C + (size_t)m * N + bn + tx * 8)     = o0;
    *(float4*)(C + (size_t)m * N + bn + tx * 8 + 4) = o1;
  }
}

__global__ void final_kernel(const float* __restrict__ a1, const float* __restrict__ w,
                             const float* __restrict__ bias, float* __restrict__ out) {
  const int b = blockIdx.x, t = threadIdx.x;
  float v = a1[b * 256 + t] * w[t];
#pragma unroll
  for (int off = 32; off > 0; off >>= 1) v += __shfl_down(v, off, 64);
  __shared__ float red[4];
  if ((t & 63) == 0) red[t >> 6] = v;
  __syncthreads();
  if (t == 0) out[b] = (red[0] + red[1]) + (red[2] + red[3]) + bias[0];
}

extern "C" void kernel_launch(void* const* d_in, const int* in_sizes, int n_in,
                              void* d_out, int out_size, void* d_ws, size_t ws_size,
                              hipStream_t stream) {
  const int*   text = (const int*)  d_in[0];
  const float* emb  = (const float*)d_in[1];
  const float* W0f  = (const float*)d_in[2];
  const float* U0f  = (const float*)d_in[3];
  const float* b0f  = (const float*)d_in[4];
  const float* W0b  = (const float*)d_in[5];
  const float* U0b  = (const float*)d_in[6];
  const float* b0b  = (const float*)d_in[7];
  const float* W1f  = (const float*)d_in[8];
  const float* U1f  = (const float*)d_in[9];
  const float* b1f  = (const float*)d_in[10];
  const float* W1b  = (const float*)d_in[11];
  const float* U1b  = (const float*)d_in[12];
  const float* b1b  = (const float*)d_in[13];
  const float* d0w  = (const float*)d_in[14];
  const float* d0b  = (const float*)d_in[15];
  const float* d1w  = (const float*)d_in[16];
  const float* d1b  = (const float*)d_in[17];
  const float* d2w  = (const float*)d_in[18];
  const float* d2b  = (const float*)d_in[19];
  float* out = (float*)d_out;

  // workspace carve: identical to proven footprint (168,955,904 B)
  char* p = (char*)d_ws;
  __half* xzA = (__half*)p;  p += (size_t)NB * NS * N4H * 2;
  __half* xzB = (__half*)p;  p += (size_t)NB * NS * N4H * 2;
  char* region1 = p;         p += (size_t)NB * NS * 1024 * 2;
  _Float16* x_emb = (_Float16*)region1;   // dead before hs0 written
  __half*   hs0   = (__half*)region1;     // layer-0 ring == hs output; layer-1 ring reuses
  __half* hp0  = (__half*)p;  p += 64 * 1024 * 2;   // unused (carve kept identical)
  __half* hp1  = (__half*)p;  p += 64 * 1024 * 2;   // unused
  int*    cnt  = (int*)p;     p += 64 * 1024 * 4;   // barrier flags + abort
  float*  feat = (float*)p;   p += 64 * 1024 * 4;
  float*  a0   = (float*)p;   p += 64 * 512 * 4;
  float*  a1   = (float*)p;   p += 64 * 256 * 4;
  (void)hp0; (void)hp1;
  int* flags0 = cnt;          // layer0: [dir*128 + cblk*4 + wave], per-wave steps
  int* flags1 = cnt + 256;    // layer1
  int* abortf = cnt + 512;

  hipMemsetAsync(cnt, 0, 520 * sizeof(int), stream);
  hipLaunchKernelGGL(embed_f16_kernel, dim3(4096), dim3(256), 0, stream, text, emb, x_emb);

  dim3 gmf(16, 128);
  hipLaunchKernelGGL(gemm_mfma_kernel, gmf, dim3(256), 0, stream, x_emb, W0f, b0f, xzA, 16384, N4H, NDP, ND);
  hipLaunchKernelGGL(gemm_mfma_kernel, gmf, dim3(256), 0, stream, x_emb, W0b, b0b, xzB, 16384, N4H, NDP, ND);

  hipLaunchKernelGGL(scan_ring_kernel, dim3(256), dim3(256), 0, stream,
                     xzA, xzB, U0f, U0b, text, hs0, flags0, abortf, (float*)nullptr);

  hipLaunchKernelGGL(gemm_mfma_kernel, gmf, dim3(256), 0, stream, (const _Float16*)hs0, W1f, b1f, xzA, 16384, N4H, 1024, 1024);
  hipLaunchKernelGGL(gemm_mfma_kernel, gmf, dim3(256), 0, stream, (const _Float16*)hs0, W1b, b1b, xzB, 16384, N4H, 1024, 1024);

  // layer-1 ring reuses region1 (hs0 dead after the two GEMMs above)
  hipLaunchKernelGGL(scan_ring_kernel, dim3(256), dim3(256), 0, stream,
                     xzA, xzB, U1f, U1b, text, hs0, flags1, abortf, feat);

  gemm_kernel<1><<<dim3(4, 1), dim3(256), 0, stream>>>(feat, d0w, d0b, a0, 64, 512, 1024);
  gemm_kernel<1><<<dim3(2, 1), dim3(256), 0, stream>>>(a0, d1w, d1b, a1, 64, 256, 512);
  hipLaunchKernelGGL(final_kernel, dim3(64), dim3(256), 0, stream, a1, d2w, d2b, out);
}

// Round 8
// 2366.220 us; speedup vs baseline: 1.6353x; 1.6353x over previous
//
// R19: batch-quarter split scan. R17/R18 micro-opts were free (no effect) =>
// 5.6us/step is structural: 64KB/block exchange + barrier fixed cost. The
// LSTM recurrence is INDEPENDENT across batch rows (z[b,:] needs only h[b,:]),
// so partition batch 4-ways as well as h-cols: 8 groups = 2 dir x 4 quarter,
// group g = 32 blocks on XCD g (b%8, perf-only). Block owns 16 rows x 16
// h-cols: staging 16KB (was 64), per-XCD L2 exchange 512KB/step (was 2MB),
// 16 MFMA/wave (was 64), 1 gate-state/thread (was 4), 4 xz loads (was 16),
// 256 CUs busy (was 64). Wave = gate; z combined via small padded LDS tile
// ([4][16][20] f32, 2-way-free reads). ufrag per thread: 16x8 halves (64
// VGPR). Protocol verbatim R17/R18 (AGENT t0-flag after __syncthreads,
// all-wave AGENT poll, abort, prefetch under RTT); per-group flag lines.
// Groups fully independent (no cross-group sync). GEMMs/embed/head/carve
// unchanged except flag area (8 groups x 32 flags x 2 layers).
#include <hip/hip_runtime.h>
#include <hip/hip_fp16.h>
#include <math.h>

#define NB   64
#define NS   256
#define ND   300
#define NDP  320
#define NH   512
#define N4H  2048

typedef _Float16 half8_t __attribute__((ext_vector_type(8)));
typedef float    f32x4_t __attribute__((ext_vector_type(4)));

typedef const __attribute__((address_space(1))) unsigned int gas_u32;
typedef __attribute__((address_space(3))) unsigned int las_u32;

__device__ __forceinline__ float fast_sig(float x) {
  return 1.f / (1.f + __expf(-x));
}
__device__ __forceinline__ float fast_tanh(float x) {
  float ax = fabsf(x);
  float e  = __expf(2.f * ax);          // inf for large ax -> r -> 1
  float r  = 1.f - 2.f / (e + 1.f);
  return copysignf(r, x);
}

// ---------- embedding: gather + fp16 convert + zero-pad K to 320 ----------
__global__ void embed_f16_kernel(const int* __restrict__ text,
                                 const float* __restrict__ emb,
                                 _Float16* __restrict__ x) {
  int idx = blockIdx.x * 256 + threadIdx.x;
  const int total = NB * NS * NDP;
  for (; idx < total; idx += gridDim.x * 256) {
    int bs = idx / NDP;
    int d  = idx - bs * NDP;
    x[idx] = (d < ND) ? (_Float16)emb[(size_t)text[bs] * ND + d] : (_Float16)0.f;
  }
}

// ---------- MFMA GEMM with in-LDS weight transpose (unchanged from R6) ----------
__global__ __launch_bounds__(256) void gemm_mfma_kernel(
    const _Float16* __restrict__ A, const float* __restrict__ W,
    const float* __restrict__ bias, __half* __restrict__ C,
    int M, int N, int K, int Kw) {
  __shared__ __align__(16) _Float16 as[128][40];
  __shared__ __align__(16) _Float16 ws16[128][40];
  __shared__ __align__(16) float    ws32[32][132];
  const int t = threadIdx.x;
  const int w = t >> 6;
  const int l = t & 63;
  const int lane16 = l & 15;
  const int kq = l >> 4;
  const int bm = blockIdx.y * 128;
  const int bn = blockIdx.x * 128;
  const int lr  = t >> 2;
  const int lsg = t & 3;
  const int wk  = t >> 3;
  const int wns = t & 7;
  const int rn  = t >> 1;
  const int rk0 = (t & 1) * 2;

  f32x4_t acc[2][8];
#pragma unroll
  for (int i = 0; i < 2; i++)
#pragma unroll
    for (int j = 0; j < 8; j++) acc[i][j] = (f32x4_t){0.f, 0.f, 0.f, 0.f};

  for (int k0 = 0; k0 < K; k0 += 32) {
#pragma unroll
    for (int h = 0; h < 2; h++) {
      int m = h * 64 + lr;
      *(uint4*)&as[m][lsg * 8] = *(const uint4*)(A + (size_t)(bm + m) * K + k0 + lsg * 8);
    }
    if (k0 + wk < Kw) {
#pragma unroll
      for (int i = 0; i < 4; i++)
        *(float4*)&ws32[wk][wns * 16 + i * 4] =
            *(const float4*)(W + (size_t)(k0 + wk) * N + bn + wns * 16 + i * 4);
    } else {
#pragma unroll
      for (int i = 0; i < 4; i++)
        *(float4*)&ws32[wk][wns * 16 + i * 4] = make_float4(0.f, 0.f, 0.f, 0.f);
    }
    __syncthreads();
#pragma unroll
    for (int g = 0; g < 2; g++) {
      int kqq = rk0 + g;
      half8_t hv;
#pragma unroll
      for (int jj = 0; jj < 8; jj++) hv[jj] = (_Float16)ws32[kqq * 8 + jj][rn];
      *(half8_t*)&ws16[rn][kqq * 8] = hv;
    }
    __syncthreads();
    half8_t afrag[2];
#pragma unroll
    for (int i = 0; i < 2; i++)
      afrag[i] = *(const half8_t*)&as[w * 32 + i * 16 + lane16][kq * 8];
#pragma unroll
    for (int j = 0; j < 8; j++) {
      half8_t bfrag = *(const half8_t*)&ws16[j * 16 + lane16][kq * 8];
#pragma unroll
      for (int i = 0; i < 2; i++)
        acc[i][j] = __builtin_amdgcn_mfma_f32_16x16x32_f16(afrag[i], bfrag, acc[i][j], 0, 0, 0);
    }
    __syncthreads();
  }
#pragma unroll
  for (int j = 0; j < 8; j++) {
    int col = bn + j * 16 + lane16;
    float bv = bias[col];
#pragma unroll
    for (int i = 0; i < 2; i++) {
      int rbase = bm + w * 32 + i * 16 + kq * 4;
#pragma unroll
      for (int r = 0; r < 4; r++)
        C[(size_t)(rbase + r) * N + col] = __float2half(acc[i][j][r] + bv);
    }
  }
}

// ---------- persistent bi-LSTM scan: batch-quarter x col split ----------
// Grid 256 x 256thr. grp = b&7 (XCD under b%8): dir = grp&1, quarter = grp>>1.
// cblk = b>>3. Block owns batch rows [quarter*16,+16) x h-cols [cblk*16,+16).
// Per group (32 blocks, one XCD): independent flag barrier; zero cross-group
// sync. Wave w computes gate w's z-tile (16x16) via 16 MFMA; z combined in
// s_z[4][16][20] (padded); thread (rr,cc) does 1 LSTM state.
__global__ __launch_bounds__(256, 1) void scan_ring_kernel(
    const __half* __restrict__ xzf, const __half* __restrict__ xzb,
    const float* __restrict__ Uf, const float* __restrict__ Ub,
    const int* __restrict__ text,
    __half* ring,
    int* flags, int* abortf,
    float* __restrict__ hT_out) {
  __shared__ __align__(16) _Float16 s_h[16 * 512];      // 16KB h stripe
  __shared__ __align__(16) float    s_z[4 * 16 * 20];   // 5KB z [gate][col][row p20]

  const int t   = threadIdx.x;
  const int b   = blockIdx.x;
  const int grp = b & 7;
  const int dir = grp & 1;
  const int q16 = (grp >> 1) * 16;     // batch-quarter row base
  const int cblk = b >> 3;             // 0..31
  const int hc0  = cblk * 16;
  const __half* xz = dir ? xzb : xzf;
  const float* U = dir ? Ub : Uf;
  int* myflags = flags + grp * 32;

  const int w    = t >> 6;          // wave = gate index
  const int lane = t & 63;
  const int l16  = lane & 15;
  const int quad = lane >> 4;

  // staging: 1024 chunks of 16B; chunk qq = i*256+t: lrow=qq>>6, ch=qq&63;
  // source chunk carries the XOR swizzle (LDS linear, rule #21)
  int st_off[4];
#pragma unroll
  for (int i = 0; i < 4; i++) {
    int qq = i * 256 + t;
    int lrow = qq >> 6, ch = qq & 63;
    st_off[i] = (q16 + lrow) * (NS * 1024) + ((ch ^ lrow) * 8);
  }
  const __half* ringd = ring + dir * NH;

  // gate-state geometry: thread owns (row rr, col cc); 1 state
  const int cc = t & 15, rr = t >> 4;
  const int gr = q16 + rr;             // global batch row
  int xz_off[4];
#pragma unroll
  for (int g = 0; g < 4; g++)
    xz_off[g] = gr * (NS * N4H) + g * NH + hc0 + cc;
  const int t_off = gr * NS;

  // persistent U B-frags for gate w: ufrag[kt][jj] = U[kt*32+quad*8+jj][w*512+hc0+l16]
  half8_t ufrag[16];
  {
    const int col = w * NH + hc0 + l16;
#pragma unroll
    for (int kt = 0; kt < 16; kt++)
#pragma unroll
      for (int jj = 0; jj < 8; jj++)
        ufrag[kt][jj] = (_Float16)U[(size_t)(kt * 32 + quad * 8 + jj) * N4H + col];
  }

  float c_st = 0.f, h_st = 0.f;
  __half xzr[4];
  int tmsk;
  {
    const int tt0 = dir ? (NS - 1) : 0;
#pragma unroll
    for (int g = 0; g < 4; g++) xzr[g] = xz[(size_t)tt0 * N4H + xz_off[g]];
    tmsk = text[t_off + tt0];
  }

  for (int s = 0; s < NS; s++) {
    const int tt = dir ? (NS - 1 - s) : s;
    f32x4_t acc = {0.f, 0.f, 0.f, 0.f};

    if (s > 0) {
      const int ttp = dir ? (tt + 1) : (tt - 1);   // slot holding h(s-1)
      const __half* srcb = ringd + (size_t)ttp * 1024;
#pragma unroll
      for (int i = 0; i < 4; i++)
        __builtin_amdgcn_global_load_lds((gas_u32*)(srcb + st_off[i]),
                                         (las_u32*)(s_h + (size_t)(i * 256 + t) * 8),
                                         16, 0, 0);
      __syncthreads();   // drains DMA + xz prefetch
      // 16 MFMA: A = h stripe (rows l16, k chunks swizzled), B = ufrag
#pragma unroll
      for (int kt = 0; kt < 16; kt++) {
        half8_t af = *(const half8_t*)(s_h + l16 * 512 + (((kt * 4 + quad)) ^ l16) * 8);
        acc = __builtin_amdgcn_mfma_f32_16x16x32_f16(af, ufrag[kt], acc, 0, 0, 0);
      }
    }

    // dump z-tile: [gate w][col l16][rows quad*4..+3]
    *(f32x4_t*)&s_z[w * 320 + l16 * 20 + quad * 4] = acc;
    __syncthreads();

    // gate update: 1 state (row rr, col cc)
    {
      float zi = s_z[0 * 320 + cc * 20 + rr] + __half2float(xzr[0]);
      float zf = s_z[1 * 320 + cc * 20 + rr] + __half2float(xzr[1]);
      float zg = s_z[2 * 320 + cc * 20 + rr] + __half2float(xzr[2]);
      float zo = s_z[3 * 320 + cc * 20 + rr] + __half2float(xzr[3]);
      float ig = fast_sig(zi);
      float fg = fast_sig(zf);
      float gv = fast_tanh(zg);
      float og = fast_sig(zo);
      float cn = fg * c_st + ig * gv;
      float hn = og * fast_tanh(cn);
      if (tmsk != 0) { c_st = cn; h_st = hn; }
      ring[((size_t)gr * NS + tt) * 1024 + dir * NH + hc0 + cc] = __float2half(h_st);
      if (hT_out && s == NS - 1)
        hT_out[(size_t)gr * 1024 + dir * NH + hc0 + cc] = h_st;
    }

    if (s < NS - 1) {
      const int ttn = dir ? (tt - 1) : (tt + 1);
      __syncthreads();   // gates done; each wave's h stores drained (vmcnt0)
      if (t == 0)
        __hip_atomic_store(myflags + cblk, s + 1, __ATOMIC_RELAXED,
                           __HIP_MEMORY_SCOPE_AGENT);
      // prefetch next xz/mask under the flag RTT
#pragma unroll
      for (int g = 0; g < 4; g++) xzr[g] = xz[(size_t)ttn * N4H + xz_off[g]];
      tmsk = text[t_off + ttn];
      // all-wave poll of this group's 32 flags (proven AGENT pattern)
      {
        int aborted = 0, it = 0;
        while (true) {
          int f = __hip_atomic_load(myflags + (lane & 31),
                                    __ATOMIC_RELAXED, __HIP_MEMORY_SCOPE_AGENT);
          if (__all(f >= s + 1)) break;
          __builtin_amdgcn_s_sleep(2);
          if (((++it) & 1023) == 0) {
            if (it > 200000)
              __hip_atomic_store(abortf, 1, __ATOMIC_RELAXED, __HIP_MEMORY_SCOPE_AGENT);
            if (__hip_atomic_load(abortf, __ATOMIC_RELAXED, __HIP_MEMORY_SCOPE_AGENT)) {
              aborted = 1; break;
            }
          }
        }
        if (aborted) return;   // wave-uniform; before any barrier -> no hang
      }
    }
  }
}

// ---------- fp32 SMEM GEMM (head only) ----------
template <int ACT>
__global__ __launch_bounds__(256) void gemm_kernel(
    const float* __restrict__ A, const float* __restrict__ W,
    const float* __restrict__ bias, float* __restrict__ C,
    int M, int N, int K) {
  __shared__ __align__(16) float As[8][128];
  __shared__ __align__(16) float Bs[8][128];
  const int t  = threadIdx.x;
  const int bn = blockIdx.x * 128;
  const int bm = blockIdx.y * 128;
  const int tx = t & 15, ty = t >> 4;
  const int lm  = t >> 1;
  const int lk4 = (t & 1) * 4;
  const int lbk = t >> 5;
  const int lbn = (t & 31) * 4;
  float acc[8][8];
#pragma unroll
  for (int i = 0; i < 8; i++)
#pragma unroll
    for (int j = 0; j < 8; j++) acc[i][j] = 0.f;

  for (int k0 = 0; k0 < K; k0 += 8) {
#pragma unroll
    for (int i = 0; i < 4; i++) {
      int k = k0 + lk4 + i;
      int m = bm + lm;
      float v = 0.f;
      if (k < K && m < M) v = A[(size_t)m * K + k];
      As[lk4 + i][lm] = v;
    }
    {
      int k = k0 + lbk;
      float4 v = make_float4(0.f, 0.f, 0.f, 0.f);
      if (k < K) v = *(const float4*)(W + (size_t)k * N + bn + lbn);
      *(float4*)(&Bs[lbk][lbn]) = v;
    }
    __syncthreads();
#pragma unroll
    for (int kk = 0; kk < 8; kk++) {
      float a[8], bb[8];
      *(float4*)(a)      = *(const float4*)(&As[kk][ty * 8]);
      *(float4*)(a + 4)  = *(const float4*)(&As[kk][ty * 8 + 4]);
      *(float4*)(bb)     = *(const float4*)(&Bs[kk][tx * 8]);
      *(float4*)(bb + 4) = *(const float4*)(&Bs[kk][tx * 8 + 4]);
#pragma unroll
      for (int i = 0; i < 8; i++)
#pragma unroll
        for (int j = 0; j < 8; j++) acc[i][j] += a[i] * bb[j];
    }
    __syncthreads();
  }
  float4 bv0 = *(const float4*)(bias + bn + tx * 8);
  float4 bv1 = *(const float4*)(bias + bn + tx * 8 + 4);
#pragma unroll
  for (int i = 0; i < 8; i++) {
    int m = bm + ty * 8 + i;
    if (m >= M) continue;
    float4 o0, o1;
    o0.x = acc[i][0] + bv0.x; o0.y = acc[i][1] + bv0.y;
    o0.z = acc[i][2] + bv0.z; o0.w = acc[i][3] + bv0.w;
    o1.x = acc[i][4] + bv1.x; o1.y = acc[i][5] + bv1.y;
    o1.z = acc[i][6] + bv1.z; o1.w = acc[i][7] + bv1.w;
    if (ACT == 1) {
      o0.x = o0.x >= 0.f ? o0.x : 0.2f * o0.x;  o0.y = o0.y >= 0.f ? o0.y : 0.2f * o0.y;
      o0.z = o0.z >= 0.f ? o0.z : 0.2f * o0.z;  o0.w = o0.w >= 0.f ? o0.w : 0.2f * o0.w;
      o1.x = o1.x >= 0.f ? o1.x : 0.2f * o1.x;  o1.y = o1.y >= 0.f ? o1.y : 0.2f * o1.y;
      o1.z = o1.z >= 0.f ? o1.z : 0.2f * o1.z;  o1.w = o1.w >= 0.f ? o1.w : 0.2f * o1.w;
    }
    *(float4*)(C + (size_t)m * N + bn + tx * 8)     = o0;
    *(float4*)(C + (size_t)m * N + bn + tx * 8 + 4) = o1;
  }
}

__global__ void final_kernel(const float* __restrict__ a1, const float* __restrict__ w,
                             const float* __restrict__ bias, float* __restrict__ out) {
  const int b = blockIdx.x, t = threadIdx.x;
  float v = a1[b * 256 + t] * w[t];
#pragma unroll
  for (int off = 32; off > 0; off >>= 1) v += __shfl_down(v, off, 64);
  __shared__ float red[4];
  if ((t & 63) == 0) red[t >> 6] = v;
  __syncthreads();
  if (t == 0) out[b] = (red[0] + red[1]) + (red[2] + red[3]) + bias[0];
}

extern "C" void kernel_launch(void* const* d_in, const int* in_sizes, int n_in,
                              void* d_out, int out_size, void* d_ws, size_t ws_size,
                              hipStream_t stream) {
  const int*   text = (const int*)  d_in[0];
  const float* emb  = (const float*)d_in[1];
  const float* W0f  = (const float*)d_in[2];
  const float* U0f  = (const float*)d_in[3];
  const float* b0f  = (const float*)d_in[4];
  const float* W0b  = (const float*)d_in[5];
  const float* U0b  = (const float*)d_in[6];
  const float* b0b  = (const float*)d_in[7];
  const float* W1f  = (const float*)d_in[8];
  const float* U1f  = (const float*)d_in[9];
  const float* b1f  = (const float*)d_in[10];
  const float* W1b  = (const float*)d_in[11];
  const float* U1b  = (const float*)d_in[12];
  const float* b1b  = (const float*)d_in[13];
  const float* d0w  = (const float*)d_in[14];
  const float* d0b  = (const float*)d_in[15];
  const float* d1w  = (const float*)d_in[16];
  const float* d1b  = (const float*)d_in[17];
  const float* d2w  = (const float*)d_in[18];
  const float* d2b  = (const float*)d_in[19];
  float* out = (float*)d_out;

  // workspace carve: identical to proven footprint (168,955,904 B)
  char* p = (char*)d_ws;
  __half* xzA = (__half*)p;  p += (size_t)NB * NS * N4H * 2;
  __half* xzB = (__half*)p;  p += (size_t)NB * NS * N4H * 2;
  char* region1 = p;         p += (size_t)NB * NS * 1024 * 2;
  _Float16* x_emb = (_Float16*)region1;   // dead before hs0 written
  __half*   hs0   = (__half*)region1;     // layer-0 ring == hs output; layer-1 ring reuses
  __half* hp0  = (__half*)p;  p += 64 * 1024 * 2;   // unused (carve kept identical)
  __half* hp1  = (__half*)p;  p += 64 * 1024 * 2;   // unused
  int*    cnt  = (int*)p;     p += 64 * 1024 * 4;   // barrier flags + abort
  float*  feat = (float*)p;   p += 64 * 1024 * 4;
  float*  a0   = (float*)p;   p += 64 * 512 * 4;
  float*  a1   = (float*)p;   p += 64 * 256 * 4;
  (void)hp0; (void)hp1;
  int* flags0 = cnt;          // layer0: [grp*32 + cblk], grp = dirx quarter
  int* flags1 = cnt + 256;    // layer1
  int* abortf = cnt + 512;

  hipMemsetAsync(cnt, 0, 516 * sizeof(int), stream);
  hipLaunchKernelGGL(embed_f16_kernel, dim3(4096), dim3(256), 0, stream, text, emb, x_emb);

  dim3 gmf(16, 128);
  hipLaunchKernelGGL(gemm_mfma_kernel, gmf, dim3(256), 0, stream, x_emb, W0f, b0f, xzA, 16384, N4H, NDP, ND);
  hipLaunchKernelGGL(gemm_mfma_kernel, gmf, dim3(256), 0, stream, x_emb, W0b, b0b, xzB, 16384, N4H, NDP, ND);

  hipLaunchKernelGGL(scan_ring_kernel, dim3(256), dim3(256), 0, stream,
                     xzA, xzB, U0f, U0b, text, hs0, flags0, abortf, (float*)nullptr);

  hipLaunchKernelGGL(gemm_mfma_kernel, gmf, dim3(256), 0, stream, (const _Float16*)hs0, W1f, b1f, xzA, 16384, N4H, 1024, 1024);
  hipLaunchKernelGGL(gemm_mfma_kernel, gmf, dim3(256), 0, stream, (const _Float16*)hs0, W1b, b1b, xzB, 16384, N4H, 1024, 1024);

  // layer-1 ring reuses region1 (hs0 dead after the two GEMMs above)
  hipLaunchKernelGGL(scan_ring_kernel, dim3(256), dim3(256), 0, stream,
                     xzA, xzB, U1f, U1b, text, hs0, flags1, abortf, feat);

  gemm_kernel<1><<<dim3(4, 1), dim3(256), 0, stream>>>(feat, d0w, d0b, a0, 64, 512, 1024);
  gemm_kernel<1><<<dim3(2, 1), dim3(256), 0, stream>>>(a0, d1w, d1b, a1, 64, 256, 512);
  hipLaunchKernelGGL(final_kernel, dim3(64), dim3(256), 0, stream, a1, d2w, d2b, out);
}